// Round 5
// baseline (372.041 us; speedup 1.0000x reference)
//
#include <hip/hip_runtime.h>

#define N_NODES 100000
#define N_EDGES 1600000
#define N_SUP 2
#define IN_DIM 256
#define OUT_DIM 64
#define N_TOT_EDGES (N_SUP * N_EDGES)   // 3,200,000
#define GM 64                           // GEMM M-tile per block
#define NBLK ((N_NODES + GM - 1) / GM)  // 1563

#define SHIFT 7                         // 128 nodes per bucket
#define BUCKN 128
#define NBUCK ((N_NODES + BUCKN - 1) / BUCKN)      // 782
#define CAP 4608                        // bucket staging cap: mean 4096, +8 sigma
#define CHUNK 4096                      // edges per bin block
#define BGRID ((N_TOT_EDGES + CHUNK - 1) / CHUNK)  // 782

typedef __attribute__((ext_vector_type(8))) short short8;   // 8 bf16
typedef __attribute__((ext_vector_type(4))) float floatx4;  // MFMA acc
typedef unsigned long long u64;

__device__ inline ushort f2bf(float f) {          // fp32 -> bf16 RNE
    unsigned u = __float_as_uint(f);
    return (ushort)((u + 0x7fffu + ((u >> 16) & 1u)) >> 16);
}
__device__ inline float bf2f(ushort h) {
    return __uint_as_float(((unsigned)h) << 16);
}

// ---------------------------------------------------------------------------
// W pre-swizzle into mfma_f32_16x16x32_bf16 B-fragment order (proven) +
// bucket-cursor init folded in.
// ---------------------------------------------------------------------------
__global__ __launch_bounds__(256) void wb_kernel(
    const float* __restrict__ W, ushort* __restrict__ Wb,
    int* __restrict__ bcur)
{
    int idx = blockIdx.x * 256 + threadIdx.x;      // 0..32767
    if (idx < NBUCK) bcur[idx] = idx * CAP;
    int j    = idx & 7;
    int lane = (idx >> 3) & 63;
    int nt   = (idx >> 9) & 7;
    int ks   = idx >> 12;
    int k = ks * 32 + (lane >> 4) * 8 + j;
    int n = nt * 16 + (lane & 15);
    Wb[idx] = f2bf(W[((size_t)(n >> 6) * IN_DIM + k) * OUT_DIM + (n & 63)]);
}

// ---------------------------------------------------------------------------
// MFMA GEMM (proven): psb[sup][node][64] bf16 = x @ W[sup]
// ---------------------------------------------------------------------------
__global__ __launch_bounds__(256) void gemm_kernel(
    const float* __restrict__ x, const ushort* __restrict__ Wb,
    ushort* __restrict__ psb)
{
    __shared__ __align__(16) ushort xs[GM][264];
    const int row0 = blockIdx.x * GM;
    const int trow = threadIdx.x >> 6;
    const int tcol = threadIdx.x & 63;

#pragma unroll
    for (int j = 0; j < 16; ++j) {
        int r = j * 4 + trow;
        int gr = row0 + r;
        if (gr > N_NODES - 1) gr = N_NODES - 1;
        float4 v = ((const float4*)x)[(size_t)gr * 64 + tcol];
        ushort4 h;
        h.x = f2bf(v.x); h.y = f2bf(v.y); h.z = f2bf(v.z); h.w = f2bf(v.w);
        *(ushort4*)&xs[r][tcol * 4] = h;
    }
    __syncthreads();

    const int wave = threadIdx.x >> 6;
    const int lane = threadIdx.x & 63;
    const int q = lane >> 4;
    const int m = lane & 15;
    const int nt0 = wave * 2;

    floatx4 acc[4][2];
#pragma unroll
    for (int mt = 0; mt < 4; ++mt)
#pragma unroll
        for (int nt = 0; nt < 2; ++nt)
            acc[mt][nt] = (floatx4){0.f, 0.f, 0.f, 0.f};

    const short8* Wbv = (const short8*)Wb;
#pragma unroll
    for (int ks = 0; ks < 8; ++ks) {
        short8 b0 = Wbv[((ks * 8) + nt0) * 64 + lane];
        short8 b1 = Wbv[((ks * 8) + nt0 + 1) * 64 + lane];
#pragma unroll
        for (int mt = 0; mt < 4; ++mt) {
            short8 a = *(const short8*)&xs[mt * 16 + m][ks * 32 + q * 8];
            acc[mt][0] = __builtin_amdgcn_mfma_f32_16x16x32_bf16(a, b0, acc[mt][0], 0, 0, 0);
            acc[mt][1] = __builtin_amdgcn_mfma_f32_16x16x32_bf16(a, b1, acc[mt][1], 0, 0, 0);
        }
    }

#pragma unroll
    for (int mt = 0; mt < 4; ++mt) {
#pragma unroll
        for (int nt = 0; nt < 2; ++nt) {
            int col = wave * 32 + nt * 16 + m;
            int sup = col >> 6, ch = col & 63;
#pragma unroll
            for (int r = 0; r < 4; ++r) {
                int row = row0 + mt * 16 + q * 4 + r;
                if (row < N_NODES)
                    psb[((size_t)sup * N_NODES + row) * OUT_DIM + ch] =
                        f2bf(acc[mt][nt][r]);
            }
        }
    }
}

// ---------------------------------------------------------------------------
// Bin (R3-proven structure, 256 thr, CHUNK 4096): route edges into
// fixed-capacity 128-node bucket staging regions.
// rec = (val:32 | srcsup:18 | dst_lo:7).
// ---------------------------------------------------------------------------
__global__ __launch_bounds__(256) void bin_kernel(
    const int* __restrict__ edge_src, const int* __restrict__ edge_dst,
    const float* __restrict__ edge_val,
    int* __restrict__ bcur, u64* __restrict__ sbuf)
{
    __shared__ int hist[NBUCK], gbase[NBUCK], cnt[NBUCK];
    const int base = blockIdx.x * CHUNK + threadIdx.x;

    u64 pk[16];
    int bk[16];
    for (int i = threadIdx.x; i < NBUCK; i += 256) hist[i] = 0;
    __syncthreads();

#pragma unroll
    for (int j = 0; j < 16; ++j) {
        int gid = base + j * 256;
        bk[j] = -1;
        if (gid < N_TOT_EDGES) {
            int dst = edge_dst[gid];
            int src = edge_src[gid];
            float val = edge_val[gid];
            int srcsup = (gid >= N_EDGES ? N_NODES : 0) + src;
            bk[j] = dst >> SHIFT;
            pk[j] = ((u64)__float_as_uint(val) << 32)
                  | (u64)(((unsigned)srcsup << SHIFT) | (unsigned)(dst & (BUCKN - 1)));
            atomicAdd(&hist[bk[j]], 1);
        }
    }
    __syncthreads();
    for (int i = threadIdx.x; i < NBUCK; i += 256) {
        int h = hist[i];
        gbase[i] = h ? atomicAdd(&bcur[i], h) : 0;
        cnt[i] = 0;
    }
    __syncthreads();
#pragma unroll
    for (int j = 0; j < 16; ++j) {
        if (bk[j] >= 0) {
            int loc = atomicAdd(&cnt[bk[j]], 1);
            size_t pos = (size_t)gbase[bk[j]] + loc;
            if (pos < (size_t)(bk[j] + 1) * CAP)   // safety clamp only
                sbuf[pos] = pk[j];
        }
    }
}

// ---------------------------------------------------------------------------
// Fused sort+gather (R3-proven logic, re-parameterized to 128-node buckets,
// 512-thr blocks): LDS 38.4 KB -> 4 blocks/CU (100% occupancy), 782 blocks
// all resident in one dispatch round (no tail).
//   sort: two-pass (hist -> scan -> counting-sort into LDS), int atomics only.
//   gather: R3's exact scalar inner loop (uniform-j __shfl broadcast,
//           4-deep psb-load ILP, register FMA, fused ReLU).
// ---------------------------------------------------------------------------
__global__ __launch_bounds__(512) void fused_kernel(
    const ushort* __restrict__ psb, const u64* __restrict__ sbuf,
    const int* __restrict__ bcur, float* __restrict__ out)
{
    __shared__ u64 srec[CAP];                        // 36,864 B
    __shared__ int h[BUCKN], sc[BUCKN], cur[BUCKN];  // 1.5 KB -> 38.4 KB total
    const int b = blockIdx.x;
    const int tid = threadIdx.x;

    int cnt = bcur[b] - b * CAP;
    if (cnt > CAP) cnt = CAP;
    const u64* sb = sbuf + (size_t)b * CAP;

    if (tid < BUCKN) h[tid] = 0;
    __syncthreads();

    // pass 1: histogram of local node ids (coalesced global read #1)
    for (int i = tid; i < cnt; i += 512)
        atomicAdd(&h[(int)(sb[i] & (BUCKN - 1))], 1);
    __syncthreads();

    // inclusive Hillis-Steele scan over 128 counts
    if (tid < BUCKN) sc[tid] = h[tid];
    __syncthreads();
    for (int off = 1; off < BUCKN; off <<= 1) {
        int add = (tid < BUCKN && tid >= off) ? sc[tid - off] : 0;
        __syncthreads();
        if (tid < BUCKN) sc[tid] += add;
        __syncthreads();
    }
    if (tid < BUCKN) cur[tid] = sc[tid] - h[tid];   // exclusive base
    __syncthreads();

    // pass 2: counting-sort into LDS (global read #2 is L2-hot: 36 KB window)
    for (int i = tid; i < cnt; i += 512) {
        u64 r = sb[i];
        int pos = atomicAdd(&cur[(int)(r & (BUCKN - 1))], 1);
        srec[pos] = r;
    }
    __syncthreads();

    // gather phase: wave w owns local nodes w*16 .. w*16+15
    const int wave = tid >> 6;
    const int lane = tid & 63;
    const int nbase = b << SHIFT;

    for (int t = 0; t < 16; ++t) {
        const int d = wave * 16 + t;
        const int e = sc[d];                       // uniform LDS reads
        const int s = e - h[d];
        float acc = 0.f;
        for (int base = s; base < e; base += 64) {
            const int n = min(64, e - base);
            u64 rr = 0;
            if (lane < n) rr = srec[base + lane];
            int rx = (int)(unsigned)rr;            // srcsup<<7 | dst_lo
            int ry = (int)(rr >> 32);              // val bits
            int j = 0;
            for (; j + 4 <= n; j += 4) {
                int   r0 = __shfl(rx, j),     r1 = __shfl(rx, j + 1);
                int   r2 = __shfl(rx, j + 2), r3 = __shfl(rx, j + 3);
                float v0 = __int_as_float(__shfl(ry, j));
                float v1 = __int_as_float(__shfl(ry, j + 1));
                float v2 = __int_as_float(__shfl(ry, j + 2));
                float v3 = __int_as_float(__shfl(ry, j + 3));
                float p0 = bf2f(psb[(size_t)((unsigned)r0 >> SHIFT) * OUT_DIM + lane]);
                float p1 = bf2f(psb[(size_t)((unsigned)r1 >> SHIFT) * OUT_DIM + lane]);
                float p2 = bf2f(psb[(size_t)((unsigned)r2 >> SHIFT) * OUT_DIM + lane]);
                float p3 = bf2f(psb[(size_t)((unsigned)r3 >> SHIFT) * OUT_DIM + lane]);
                acc = fmaf(p0, v0, acc);
                acc = fmaf(p1, v1, acc);
                acc = fmaf(p2, v2, acc);
                acc = fmaf(p3, v3, acc);
            }
            for (; j < n; ++j) {
                int   r0 = __shfl(rx, j);
                float v0 = __int_as_float(__shfl(ry, j));
                acc = fmaf(bf2f(psb[(size_t)((unsigned)r0 >> SHIFT) * OUT_DIM + lane]),
                           v0, acc);
            }
        }
        const int node = nbase + d;
        if (node < N_NODES)
            out[(size_t)node * OUT_DIM + lane] = fmaxf(acc, 0.f);
    }
}

extern "C" void kernel_launch(void* const* d_in, const int* in_sizes, int n_in,
                              void* d_out, int out_size, void* d_ws, size_t ws_size,
                              hipStream_t stream)
{
    const float* x        = (const float*)d_in[0];
    const float* W        = (const float*)d_in[1];
    const float* edge_val = (const float*)d_in[2];
    const int*   edge_src = (const int*)d_in[3];
    const int*   edge_dst = (const int*)d_in[4];
    float* out = (float*)d_out;

    // workspace layout (total 54,496,768 B, well under proven 77.67 MB):
    //   psb  [2*100000*64 bf16]   @ 0           (25,600,000)
    //   sbuf [782*4608 u64]       @ 25,600,000  (28,827,648)  fixed-cap staging
    //   bcur [782 int]            @ 54,427,648  (3,128)
    //   Wb   [32768 ushort]       @ 54,431,232  (65,536)  16B-aligned
    ushort* psb = (ushort*)d_ws;
    char* p = (char*)d_ws;
    u64*  sbuf = (u64*)(p + 25600000);
    int*  bcur = (int*)(p + 54427648);
    ushort* Wb = (ushort*)(p + 54431232);

    wb_kernel<<<128, 256, 0, stream>>>(W, Wb, bcur);
    gemm_kernel<<<NBLK, 256, 0, stream>>>(x, Wb, psb);
    bin_kernel<<<BGRID, 256, 0, stream>>>(edge_src, edge_dst, edge_val,
                                          bcur, sbuf);
    fused_kernel<<<NBUCK, 512, 0, stream>>>(psb, sbuf, bcur, out);
}

// Round 6
// 324.389 us; speedup vs baseline: 1.1469x; 1.1469x over previous
//
#include <hip/hip_runtime.h>

#define N_NODES 100000
#define N_EDGES 1600000
#define N_SUP 2
#define IN_DIM 256
#define OUT_DIM 64
#define N_TOT_EDGES (N_SUP * N_EDGES)   // 3,200,000
#define GM 64                           // GEMM M-tile per block
#define NBLK ((N_NODES + GM - 1) / GM)  // 1563

#define SHIFT 7                         // 128 nodes per bucket
#define BUCKN 128
#define NBUCK ((N_NODES + BUCKN - 1) / BUCKN)      // 782
#define CAP 4608                        // bucket staging cap: mean 4092, +8 sigma
#define CHUNK 4096                      // edges per bin block
#define BGRID ((N_TOT_EDGES + CHUNK - 1) / CHUNK)  // 782

typedef __attribute__((ext_vector_type(8))) short short8;   // 8 bf16
typedef __attribute__((ext_vector_type(4))) float floatx4;  // MFMA acc
typedef unsigned long long u64;

__device__ inline ushort f2bf(float f) {          // fp32 -> bf16 RNE
    unsigned u = __float_as_uint(f);
    return (ushort)((u + 0x7fffu + ((u >> 16) & 1u)) >> 16);
}
__device__ inline float bf2f(ushort h) {
    return __uint_as_float(((unsigned)h) << 16);
}

// ---------------------------------------------------------------------------
// W pre-swizzle into mfma_f32_16x16x32_bf16 B-fragment order (proven) +
// bucket-cursor init folded in.
// ---------------------------------------------------------------------------
__global__ __launch_bounds__(256) void wb_kernel(
    const float* __restrict__ W, ushort* __restrict__ Wb,
    int* __restrict__ bcur)
{
    int idx = blockIdx.x * 256 + threadIdx.x;      // 0..32767
    if (idx < NBUCK) bcur[idx] = idx * CAP;
    int j    = idx & 7;
    int lane = (idx >> 3) & 63;
    int nt   = (idx >> 9) & 7;
    int ks   = idx >> 12;
    int k = ks * 32 + (lane >> 4) * 8 + j;
    int n = nt * 16 + (lane & 15);
    Wb[idx] = f2bf(W[((size_t)(n >> 6) * IN_DIM + k) * OUT_DIM + (n & 63)]);
}

// ---------------------------------------------------------------------------
// MFMA GEMM (proven): psb[sup][node][64] bf16 = x @ W[sup]
// ---------------------------------------------------------------------------
__global__ __launch_bounds__(256) void gemm_kernel(
    const float* __restrict__ x, const ushort* __restrict__ Wb,
    ushort* __restrict__ psb)
{
    __shared__ __align__(16) ushort xs[GM][264];
    const int row0 = blockIdx.x * GM;
    const int trow = threadIdx.x >> 6;
    const int tcol = threadIdx.x & 63;

#pragma unroll
    for (int j = 0; j < 16; ++j) {
        int r = j * 4 + trow;
        int gr = row0 + r;
        if (gr > N_NODES - 1) gr = N_NODES - 1;
        float4 v = ((const float4*)x)[(size_t)gr * 64 + tcol];
        ushort4 h;
        h.x = f2bf(v.x); h.y = f2bf(v.y); h.z = f2bf(v.z); h.w = f2bf(v.w);
        *(ushort4*)&xs[r][tcol * 4] = h;
    }
    __syncthreads();

    const int wave = threadIdx.x >> 6;
    const int lane = threadIdx.x & 63;
    const int q = lane >> 4;
    const int m = lane & 15;
    const int nt0 = wave * 2;

    floatx4 acc[4][2];
#pragma unroll
    for (int mt = 0; mt < 4; ++mt)
#pragma unroll
        for (int nt = 0; nt < 2; ++nt)
            acc[mt][nt] = (floatx4){0.f, 0.f, 0.f, 0.f};

    const short8* Wbv = (const short8*)Wb;
#pragma unroll
    for (int ks = 0; ks < 8; ++ks) {
        short8 b0 = Wbv[((ks * 8) + nt0) * 64 + lane];
        short8 b1 = Wbv[((ks * 8) + nt0 + 1) * 64 + lane];
#pragma unroll
        for (int mt = 0; mt < 4; ++mt) {
            short8 a = *(const short8*)&xs[mt * 16 + m][ks * 32 + q * 8];
            acc[mt][0] = __builtin_amdgcn_mfma_f32_16x16x32_bf16(a, b0, acc[mt][0], 0, 0, 0);
            acc[mt][1] = __builtin_amdgcn_mfma_f32_16x16x32_bf16(a, b1, acc[mt][1], 0, 0, 0);
        }
    }

#pragma unroll
    for (int mt = 0; mt < 4; ++mt) {
#pragma unroll
        for (int nt = 0; nt < 2; ++nt) {
            int col = wave * 32 + nt * 16 + m;
            int sup = col >> 6, ch = col & 63;
#pragma unroll
            for (int r = 0; r < 4; ++r) {
                int row = row0 + mt * 16 + q * 4 + r;
                if (row < N_NODES)
                    psb[((size_t)sup * N_NODES + row) * OUT_DIM + ch] =
                        f2bf(acc[mt][nt][r]);
            }
        }
    }
}

// ---------------------------------------------------------------------------
// Bin (R5-proven, unchanged): route edges into fixed-capacity 128-node bucket
// staging regions. rec = (val:32 | srcsup:18 | dst_lo:7).
// ---------------------------------------------------------------------------
__global__ __launch_bounds__(256) void bin_kernel(
    const int* __restrict__ edge_src, const int* __restrict__ edge_dst,
    const float* __restrict__ edge_val,
    int* __restrict__ bcur, u64* __restrict__ sbuf)
{
    __shared__ int hist[NBUCK], gbase[NBUCK], cnt[NBUCK];
    const int base = blockIdx.x * CHUNK + threadIdx.x;

    u64 pk[16];
    int bk[16];
    for (int i = threadIdx.x; i < NBUCK; i += 256) hist[i] = 0;
    __syncthreads();

#pragma unroll
    for (int j = 0; j < 16; ++j) {
        int gid = base + j * 256;
        bk[j] = -1;
        if (gid < N_TOT_EDGES) {
            int dst = edge_dst[gid];
            int src = edge_src[gid];
            float val = edge_val[gid];
            int srcsup = (gid >= N_EDGES ? N_NODES : 0) + src;
            bk[j] = dst >> SHIFT;
            pk[j] = ((u64)__float_as_uint(val) << 32)
                  | (u64)(((unsigned)srcsup << SHIFT) | (unsigned)(dst & (BUCKN - 1)));
            atomicAdd(&hist[bk[j]], 1);
        }
    }
    __syncthreads();
    for (int i = threadIdx.x; i < NBUCK; i += 256) {
        int h = hist[i];
        gbase[i] = h ? atomicAdd(&bcur[i], h) : 0;
        cnt[i] = 0;
    }
    __syncthreads();
#pragma unroll
    for (int j = 0; j < 16; ++j) {
        if (bk[j] >= 0) {
            int loc = atomicAdd(&cnt[bk[j]], 1);
            size_t pos = (size_t)gbase[bk[j]] + loc;
            if (pos < (size_t)(bk[j] + 1) * CAP)   // safety clamp only
                sbuf[pos] = pk[j];
        }
    }
}

// ---------------------------------------------------------------------------
// Fused sort+gather. Sort phase is R5-VERBATIM (two-pass: hist -> scan ->
// counting-sort into LDS, int atomics only). Gather phase is the one change
// this round: 4-edge vectorized layout with direct LDS record reads --
//   grp=lane>>4 selects the edge, cl=lane&15 the channel quad.
//   per 4 edges: 1 ds_read_b64 (vs 8 ds_bpermute before) + 1 vmem ushort4
//   load (vs 4 scalar loads). 16 edges in flight per iteration. Tail is
//   branchless: rec=0 => val=0 => fma contributes 0 (psb row 0 load is
//   harmless). Cross-group shfl_xor(16,32) reduce, float4 coalesced store.
// ---------------------------------------------------------------------------
__global__ __launch_bounds__(512) void fused_kernel(
    const ushort* __restrict__ psb, const u64* __restrict__ sbuf,
    const int* __restrict__ bcur, float* __restrict__ out)
{
    __shared__ u64 srec[CAP];                        // 36,864 B
    __shared__ int h[BUCKN], sc[BUCKN], cur[BUCKN];  // 1.5 KB -> 38.4 KB total
    const int b = blockIdx.x;
    const int tid = threadIdx.x;

    int cnt = bcur[b] - b * CAP;
    if (cnt > CAP) cnt = CAP;
    const u64* sb = sbuf + (size_t)b * CAP;

    if (tid < BUCKN) h[tid] = 0;
    __syncthreads();

    // pass 1: histogram of local node ids (coalesced global read #1)
    for (int i = tid; i < cnt; i += 512)
        atomicAdd(&h[(int)(sb[i] & (BUCKN - 1))], 1);
    __syncthreads();

    // inclusive Hillis-Steele scan over 128 counts
    if (tid < BUCKN) sc[tid] = h[tid];
    __syncthreads();
    for (int off = 1; off < BUCKN; off <<= 1) {
        int add = (tid < BUCKN && tid >= off) ? sc[tid - off] : 0;
        __syncthreads();
        if (tid < BUCKN) sc[tid] += add;
        __syncthreads();
    }
    if (tid < BUCKN) cur[tid] = sc[tid] - h[tid];   // exclusive base
    __syncthreads();

    // pass 2: counting-sort into LDS (global read #2 is L2-hot: 36 KB window)
    for (int i = tid; i < cnt; i += 512) {
        u64 r = sb[i];
        int pos = atomicAdd(&cur[(int)(r & (BUCKN - 1))], 1);
        srec[pos] = r;
    }
    __syncthreads();

    // gather phase: wave w owns local nodes w*16 .. w*16+15
    const int wave = tid >> 6;
    const int lane = tid & 63;
    const int grp  = lane >> 4;     // which edge of a 4-edge chunk
    const int cl   = lane & 15;     // which channel quad
    const int nbase = b << SHIFT;

    for (int t = 0; t < 16; ++t) {
        const int d = wave * 16 + t;
        const int e = sc[d];                       // uniform LDS reads
        const int s = e - h[d];
        float4 acc = {0.f, 0.f, 0.f, 0.f};

        for (int jb = s; jb < e; jb += 16) {       // 16 edges per iteration
            int i0 = jb + grp, i1 = jb + 4 + grp, i2 = jb + 8 + grp, i3 = jb + 12 + grp;
            u64 r0 = 0, r1 = 0, r2 = 0, r3 = 0;
            if (i0 < e) r0 = srec[i0];
            if (i1 < e) r1 = srec[i1];
            if (i2 < e) r2 = srec[i2];
            if (i3 < e) r3 = srec[i3];
            // rec==0 => val bits 0 => fma adds 0; row 0 load is harmless
            float v0 = __uint_as_float((unsigned)(r0 >> 32));
            float v1 = __uint_as_float((unsigned)(r1 >> 32));
            float v2 = __uint_as_float((unsigned)(r2 >> 32));
            float v3 = __uint_as_float((unsigned)(r3 >> 32));
            unsigned w0 = (unsigned)r0 >> SHIFT;
            unsigned w1 = (unsigned)r1 >> SHIFT;
            unsigned w2 = (unsigned)r2 >> SHIFT;
            unsigned w3 = (unsigned)r3 >> SHIFT;
            ushort4 p0 = *(const ushort4*)&psb[(size_t)w0 * OUT_DIM + cl * 4];
            ushort4 p1 = *(const ushort4*)&psb[(size_t)w1 * OUT_DIM + cl * 4];
            ushort4 p2 = *(const ushort4*)&psb[(size_t)w2 * OUT_DIM + cl * 4];
            ushort4 p3 = *(const ushort4*)&psb[(size_t)w3 * OUT_DIM + cl * 4];
            acc.x = fmaf(bf2f(p0.x), v0, acc.x);
            acc.y = fmaf(bf2f(p0.y), v0, acc.y);
            acc.z = fmaf(bf2f(p0.z), v0, acc.z);
            acc.w = fmaf(bf2f(p0.w), v0, acc.w);
            acc.x = fmaf(bf2f(p1.x), v1, acc.x);
            acc.y = fmaf(bf2f(p1.y), v1, acc.y);
            acc.z = fmaf(bf2f(p1.z), v1, acc.z);
            acc.w = fmaf(bf2f(p1.w), v1, acc.w);
            acc.x = fmaf(bf2f(p2.x), v2, acc.x);
            acc.y = fmaf(bf2f(p2.y), v2, acc.y);
            acc.z = fmaf(bf2f(p2.z), v2, acc.z);
            acc.w = fmaf(bf2f(p2.w), v2, acc.w);
            acc.x = fmaf(bf2f(p3.x), v3, acc.x);
            acc.y = fmaf(bf2f(p3.y), v3, acc.y);
            acc.z = fmaf(bf2f(p3.z), v3, acc.z);
            acc.w = fmaf(bf2f(p3.w), v3, acc.w);
        }

        // reduce the 4 edge-groups (channels cl*4.. live in lanes cl, cl+16, cl+32, cl+48)
        acc.x += __shfl_xor(acc.x, 16); acc.x += __shfl_xor(acc.x, 32);
        acc.y += __shfl_xor(acc.y, 16); acc.y += __shfl_xor(acc.y, 32);
        acc.z += __shfl_xor(acc.z, 16); acc.z += __shfl_xor(acc.z, 32);
        acc.w += __shfl_xor(acc.w, 16); acc.w += __shfl_xor(acc.w, 32);

        const int node = nbase + d;
        if (lane < 16 && node < N_NODES) {
            acc.x = fmaxf(acc.x, 0.f); acc.y = fmaxf(acc.y, 0.f);
            acc.z = fmaxf(acc.z, 0.f); acc.w = fmaxf(acc.w, 0.f);
            ((float4*)out)[(size_t)node * 16 + cl] = acc;
        }
    }
}

extern "C" void kernel_launch(void* const* d_in, const int* in_sizes, int n_in,
                              void* d_out, int out_size, void* d_ws, size_t ws_size,
                              hipStream_t stream)
{
    const float* x        = (const float*)d_in[0];
    const float* W        = (const float*)d_in[1];
    const float* edge_val = (const float*)d_in[2];
    const int*   edge_src = (const int*)d_in[3];
    const int*   edge_dst = (const int*)d_in[4];
    float* out = (float*)d_out;

    // workspace layout (total 54,496,768 B, well under proven 77.67 MB):
    //   psb  [2*100000*64 bf16]   @ 0           (25,600,000)
    //   sbuf [782*4608 u64]       @ 25,600,000  (28,827,648)  fixed-cap staging
    //   bcur [782 int]            @ 54,427,648  (3,128)
    //   Wb   [32768 ushort]       @ 54,431,232  (65,536)  16B-aligned
    ushort* psb = (ushort*)d_ws;
    char* p = (char*)d_ws;
    u64*  sbuf = (u64*)(p + 25600000);
    int*  bcur = (int*)(p + 54427648);
    ushort* Wb = (ushort*)(p + 54431232);

    wb_kernel<<<128, 256, 0, stream>>>(W, Wb, bcur);
    gemm_kernel<<<NBLK, 256, 0, stream>>>(x, Wb, psb);
    bin_kernel<<<BGRID, 256, 0, stream>>>(edge_src, edge_dst, edge_val,
                                          bcur, sbuf);
    fused_kernel<<<NBUCK, 512, 0, stream>>>(psb, sbuf, bcur, out);
}

// Round 7
// 321.525 us; speedup vs baseline: 1.1571x; 1.0089x over previous
//
#include <hip/hip_runtime.h>

#define N_NODES 100000
#define N_EDGES 1600000
#define N_SUP 2
#define IN_DIM 256
#define OUT_DIM 64
#define N_TOT_EDGES (N_SUP * N_EDGES)   // 3,200,000
#define GM 64                           // GEMM M-tile per block
#define NBLK ((N_NODES + GM - 1) / GM)  // 1563

#define SHIFT 7                         // 128 nodes per bucket
#define BUCKN 128
#define NBUCK ((N_NODES + BUCKN - 1) / BUCKN)      // 782
#define CAP 4608                        // bucket staging cap: mean 4092, +8 sigma
#define CHUNK 4096                      // edges per bin block
#define BGRID ((N_TOT_EDGES + CHUNK - 1) / CHUNK)  // 782

typedef __attribute__((ext_vector_type(8))) short short8;   // 8 bf16
typedef __attribute__((ext_vector_type(4))) float floatx4;  // MFMA acc
typedef unsigned long long u64;

__device__ inline ushort f2bf(float f) {          // fp32 -> bf16 RNE
    unsigned u = __float_as_uint(f);
    return (ushort)((u + 0x7fffu + ((u >> 16) & 1u)) >> 16);
}
__device__ inline float bf2f(ushort h) {
    return __uint_as_float(((unsigned)h) << 16);
}

// ---------------------------------------------------------------------------
// W pre-swizzle into mfma_f32_16x16x32_bf16 B-fragment order (proven) +
// bucket-cursor init folded in.
// ---------------------------------------------------------------------------
__global__ __launch_bounds__(256) void wb_kernel(
    const float* __restrict__ W, ushort* __restrict__ Wb,
    int* __restrict__ bcur)
{
    int idx = blockIdx.x * 256 + threadIdx.x;      // 0..32767
    if (idx < NBUCK) bcur[idx] = idx * CAP;
    int j    = idx & 7;
    int lane = (idx >> 3) & 63;
    int nt   = (idx >> 9) & 7;
    int ks   = idx >> 12;
    int k = ks * 32 + (lane >> 4) * 8 + j;
    int n = nt * 16 + (lane & 15);
    Wb[idx] = f2bf(W[((size_t)(n >> 6) * IN_DIM + k) * OUT_DIM + (n & 63)]);
}

// ---------------------------------------------------------------------------
// MFMA GEMM (proven): psb[sup][node][64] bf16 = x @ W[sup]
// ---------------------------------------------------------------------------
__global__ __launch_bounds__(256) void gemm_kernel(
    const float* __restrict__ x, const ushort* __restrict__ Wb,
    ushort* __restrict__ psb)
{
    __shared__ __align__(16) ushort xs[GM][264];
    const int row0 = blockIdx.x * GM;
    const int trow = threadIdx.x >> 6;
    const int tcol = threadIdx.x & 63;

#pragma unroll
    for (int j = 0; j < 16; ++j) {
        int r = j * 4 + trow;
        int gr = row0 + r;
        if (gr > N_NODES - 1) gr = N_NODES - 1;
        float4 v = ((const float4*)x)[(size_t)gr * 64 + tcol];
        ushort4 h;
        h.x = f2bf(v.x); h.y = f2bf(v.y); h.z = f2bf(v.z); h.w = f2bf(v.w);
        *(ushort4*)&xs[r][tcol * 4] = h;
    }
    __syncthreads();

    const int wave = threadIdx.x >> 6;
    const int lane = threadIdx.x & 63;
    const int q = lane >> 4;
    const int m = lane & 15;
    const int nt0 = wave * 2;

    floatx4 acc[4][2];
#pragma unroll
    for (int mt = 0; mt < 4; ++mt)
#pragma unroll
        for (int nt = 0; nt < 2; ++nt)
            acc[mt][nt] = (floatx4){0.f, 0.f, 0.f, 0.f};

    const short8* Wbv = (const short8*)Wb;
#pragma unroll
    for (int ks = 0; ks < 8; ++ks) {
        short8 b0 = Wbv[((ks * 8) + nt0) * 64 + lane];
        short8 b1 = Wbv[((ks * 8) + nt0 + 1) * 64 + lane];
#pragma unroll
        for (int mt = 0; mt < 4; ++mt) {
            short8 a = *(const short8*)&xs[mt * 16 + m][ks * 32 + q * 8];
            acc[mt][0] = __builtin_amdgcn_mfma_f32_16x16x32_bf16(a, b0, acc[mt][0], 0, 0, 0);
            acc[mt][1] = __builtin_amdgcn_mfma_f32_16x16x32_bf16(a, b1, acc[mt][1], 0, 0, 0);
        }
    }

#pragma unroll
    for (int mt = 0; mt < 4; ++mt) {
#pragma unroll
        for (int nt = 0; nt < 2; ++nt) {
            int col = wave * 32 + nt * 16 + m;
            int sup = col >> 6, ch = col & 63;
#pragma unroll
            for (int r = 0; r < 4; ++r) {
                int row = row0 + mt * 16 + q * 4 + r;
                if (row < N_NODES)
                    psb[((size_t)sup * N_NODES + row) * OUT_DIM + ch] =
                        f2bf(acc[mt][nt][r]);
            }
        }
    }
}

// ---------------------------------------------------------------------------
// Bin with rank trick: the hist atomic's return value IS the record's slot
// within the block's per-bucket run -> the second (cnt cursor) atomic is
// deleted. pos = gbase[bk] + rank. 1 LDS atomic per edge instead of 2.
// rec = (val:32 | srcsup:18 | dst_lo:7).
// ---------------------------------------------------------------------------
__global__ __launch_bounds__(256) void bin_kernel(
    const int* __restrict__ edge_src, const int* __restrict__ edge_dst,
    const float* __restrict__ edge_val,
    int* __restrict__ bcur, u64* __restrict__ sbuf)
{
    __shared__ int hist[NBUCK], gbase[NBUCK];
    const int base = blockIdx.x * CHUNK + threadIdx.x;

    u64 pk[16];
    int bk[16];
    int rk[16];
    for (int i = threadIdx.x; i < NBUCK; i += 256) hist[i] = 0;
    __syncthreads();

#pragma unroll
    for (int j = 0; j < 16; ++j) {
        int gid = base + j * 256;
        bk[j] = -1;
        if (gid < N_TOT_EDGES) {
            int dst = edge_dst[gid];
            int src = edge_src[gid];
            float val = edge_val[gid];
            int srcsup = (gid >= N_EDGES ? N_NODES : 0) + src;
            bk[j] = dst >> SHIFT;
            pk[j] = ((u64)__float_as_uint(val) << 32)
                  | (u64)(((unsigned)srcsup << SHIFT) | (unsigned)(dst & (BUCKN - 1)));
            rk[j] = atomicAdd(&hist[bk[j]], 1);
        }
    }
    __syncthreads();
    for (int i = threadIdx.x; i < NBUCK; i += 256) {
        int h = hist[i];
        gbase[i] = h ? atomicAdd(&bcur[i], h) : 0;
    }
    __syncthreads();
#pragma unroll
    for (int j = 0; j < 16; ++j) {
        if (bk[j] >= 0) {
            size_t pos = (size_t)gbase[bk[j]] + rk[j];
            if (pos < (size_t)(bk[j] + 1) * CAP)   // safety clamp only
                sbuf[pos] = pk[j];
        }
    }
}

// ---------------------------------------------------------------------------
// Fused sort+gather. Sort phase now single-global-pass with the rank trick:
// records + ranks (from the hist atomic) held in registers through the scan,
// then scattered to srec[eb[node]+rank] with NO cursor atomic and NO second
// global read of sbuf (-28.8 MB fetch). Gather phase is R6-VERBATIM
// (4-edge vectorized direct-LDS-read layout, branchless tail, shfl_xor
// cross-group reduce, float4 store).
// ---------------------------------------------------------------------------
__global__ __launch_bounds__(512) void fused_kernel(
    const ushort* __restrict__ psb, const u64* __restrict__ sbuf,
    const int* __restrict__ bcur, float* __restrict__ out)
{
    __shared__ u64 srec[CAP];                        // 36,864 B
    __shared__ int h[BUCKN], sc[BUCKN], eb[BUCKN];   // 1.5 KB -> 38.4 KB total
    const int b = blockIdx.x;
    const int tid = threadIdx.x;

    int cnt = bcur[b] - b * CAP;
    if (cnt > CAP) cnt = CAP;
    const u64* sb = sbuf + (size_t)b * CAP;

    if (tid < BUCKN) h[tid] = 0;
    __syncthreads();

    // single global pass: records -> registers, rank from hist atomic
    u64 pk[9];
    int rk[9];
#pragma unroll
    for (int jj = 0; jj < 9; ++jj) {
        int i = tid + jj * 512;
        rk[jj] = -1;
        if (i < cnt) {
            pk[jj] = sb[i];
            rk[jj] = atomicAdd(&h[(int)(pk[jj] & (BUCKN - 1))], 1);
        }
    }
    __syncthreads();

    // inclusive Hillis-Steele scan over 128 counts
    if (tid < BUCKN) sc[tid] = h[tid];
    __syncthreads();
    for (int off = 1; off < BUCKN; off <<= 1) {
        int add = (tid < BUCKN && tid >= off) ? sc[tid - off] : 0;
        __syncthreads();
        if (tid < BUCKN) sc[tid] += add;
        __syncthreads();
    }
    if (tid < BUCKN) eb[tid] = sc[tid] - h[tid];    // exclusive base
    __syncthreads();

    // scatter from registers: slot = exclusive base + rank (bijective)
#pragma unroll
    for (int jj = 0; jj < 9; ++jj) {
        if (rk[jj] >= 0) {
            int node = (int)(pk[jj] & (BUCKN - 1));
            srec[eb[node] + rk[jj]] = pk[jj];
        }
    }
    __syncthreads();

    // gather phase (R6-verbatim): wave w owns local nodes w*16 .. w*16+15
    const int wave = tid >> 6;
    const int lane = tid & 63;
    const int grp  = lane >> 4;     // which edge of a 4-edge chunk
    const int cl   = lane & 15;     // which channel quad
    const int nbase = b << SHIFT;

    for (int t = 0; t < 16; ++t) {
        const int d = wave * 16 + t;
        const int e = sc[d];                       // uniform LDS reads
        const int s = e - h[d];
        float4 acc = {0.f, 0.f, 0.f, 0.f};

        for (int jb = s; jb < e; jb += 16) {       // 16 edges per iteration
            int i0 = jb + grp, i1 = jb + 4 + grp, i2 = jb + 8 + grp, i3 = jb + 12 + grp;
            u64 r0 = 0, r1 = 0, r2 = 0, r3 = 0;
            if (i0 < e) r0 = srec[i0];
            if (i1 < e) r1 = srec[i1];
            if (i2 < e) r2 = srec[i2];
            if (i3 < e) r3 = srec[i3];
            // rec==0 => val bits 0 => fma adds 0; row 0 load is harmless
            float v0 = __uint_as_float((unsigned)(r0 >> 32));
            float v1 = __uint_as_float((unsigned)(r1 >> 32));
            float v2 = __uint_as_float((unsigned)(r2 >> 32));
            float v3 = __uint_as_float((unsigned)(r3 >> 32));
            unsigned w0 = (unsigned)r0 >> SHIFT;
            unsigned w1 = (unsigned)r1 >> SHIFT;
            unsigned w2 = (unsigned)r2 >> SHIFT;
            unsigned w3 = (unsigned)r3 >> SHIFT;
            ushort4 p0 = *(const ushort4*)&psb[(size_t)w0 * OUT_DIM + cl * 4];
            ushort4 p1 = *(const ushort4*)&psb[(size_t)w1 * OUT_DIM + cl * 4];
            ushort4 p2 = *(const ushort4*)&psb[(size_t)w2 * OUT_DIM + cl * 4];
            ushort4 p3 = *(const ushort4*)&psb[(size_t)w3 * OUT_DIM + cl * 4];
            acc.x = fmaf(bf2f(p0.x), v0, acc.x);
            acc.y = fmaf(bf2f(p0.y), v0, acc.y);
            acc.z = fmaf(bf2f(p0.z), v0, acc.z);
            acc.w = fmaf(bf2f(p0.w), v0, acc.w);
            acc.x = fmaf(bf2f(p1.x), v1, acc.x);
            acc.y = fmaf(bf2f(p1.y), v1, acc.y);
            acc.z = fmaf(bf2f(p1.z), v1, acc.z);
            acc.w = fmaf(bf2f(p1.w), v1, acc.w);
            acc.x = fmaf(bf2f(p2.x), v2, acc.x);
            acc.y = fmaf(bf2f(p2.y), v2, acc.y);
            acc.z = fmaf(bf2f(p2.z), v2, acc.z);
            acc.w = fmaf(bf2f(p2.w), v2, acc.w);
            acc.x = fmaf(bf2f(p3.x), v3, acc.x);
            acc.y = fmaf(bf2f(p3.y), v3, acc.y);
            acc.z = fmaf(bf2f(p3.z), v3, acc.z);
            acc.w = fmaf(bf2f(p3.w), v3, acc.w);
        }

        // reduce the 4 edge-groups (channels cl*4.. live in lanes cl, cl+16, cl+32, cl+48)
        acc.x += __shfl_xor(acc.x, 16); acc.x += __shfl_xor(acc.x, 32);
        acc.y += __shfl_xor(acc.y, 16); acc.y += __shfl_xor(acc.y, 32);
        acc.z += __shfl_xor(acc.z, 16); acc.z += __shfl_xor(acc.z, 32);
        acc.w += __shfl_xor(acc.w, 16); acc.w += __shfl_xor(acc.w, 32);

        const int node = nbase + d;
        if (lane < 16 && node < N_NODES) {
            acc.x = fmaxf(acc.x, 0.f); acc.y = fmaxf(acc.y, 0.f);
            acc.z = fmaxf(acc.z, 0.f); acc.w = fmaxf(acc.w, 0.f);
            ((float4*)out)[(size_t)node * 16 + cl] = acc;
        }
    }
}

extern "C" void kernel_launch(void* const* d_in, const int* in_sizes, int n_in,
                              void* d_out, int out_size, void* d_ws, size_t ws_size,
                              hipStream_t stream)
{
    const float* x        = (const float*)d_in[0];
    const float* W        = (const float*)d_in[1];
    const float* edge_val = (const float*)d_in[2];
    const int*   edge_src = (const int*)d_in[3];
    const int*   edge_dst = (const int*)d_in[4];
    float* out = (float*)d_out;

    // workspace layout (total 54,496,768 B, well under proven 77.67 MB):
    //   psb  [2*100000*64 bf16]   @ 0           (25,600,000)
    //   sbuf [782*4608 u64]       @ 25,600,000  (28,827,648)  fixed-cap staging
    //   bcur [782 int]            @ 54,427,648  (3,128)
    //   Wb   [32768 ushort]       @ 54,431,232  (65,536)  16B-aligned
    ushort* psb = (ushort*)d_ws;
    char* p = (char*)d_ws;
    u64*  sbuf = (u64*)(p + 25600000);
    int*  bcur = (int*)(p + 54427648);
    ushort* Wb = (ushort*)(p + 54431232);

    wb_kernel<<<128, 256, 0, stream>>>(W, Wb, bcur);
    gemm_kernel<<<NBLK, 256, 0, stream>>>(x, Wb, psb);
    bin_kernel<<<BGRID, 256, 0, stream>>>(edge_src, edge_dst, edge_val,
                                          bcur, sbuf);
    fused_kernel<<<NBUCK, 512, 0, stream>>>(psb, sbuf, bcur, out);
}

// Round 8
// 300.123 us; speedup vs baseline: 1.2396x; 1.0713x over previous
//
#include <hip/hip_runtime.h>

#define N_NODES 100000
#define N_EDGES 1600000
#define N_SUP 2
#define IN_DIM 256
#define OUT_DIM 64
#define N_TOT_EDGES (N_SUP * N_EDGES)   // 3,200,000
#define GM 64                           // GEMM M-tile per block
#define NBLK ((N_NODES + GM - 1) / GM)  // 1563

#define SHIFT 7                         // 128 nodes per bucket
#define BUCKN 128
#define NBUCK ((N_NODES + BUCKN - 1) / BUCKN)      // 782
#define CAP 4608                        // bucket staging cap: mean 4092, +8 sigma
#define CHUNK 4096                      // edges per bin block
#define BGRID ((N_TOT_EDGES + CHUNK - 1) / CHUNK)  // 782

typedef __attribute__((ext_vector_type(8))) short short8;   // 8 bf16
typedef __attribute__((ext_vector_type(4))) float floatx4;  // MFMA acc
typedef unsigned long long u64;

__device__ inline ushort f2bf(float f) {          // fp32 -> bf16 RNE
    unsigned u = __float_as_uint(f);
    return (ushort)((u + 0x7fffu + ((u >> 16) & 1u)) >> 16);
}
__device__ inline float bf2f(ushort h) {
    return __uint_as_float(((unsigned)h) << 16);
}

// ---------------------------------------------------------------------------
// W pre-swizzle into mfma_f32_16x16x32_bf16 B-fragment order (proven) +
// bucket-cursor init folded in.
// ---------------------------------------------------------------------------
__global__ __launch_bounds__(256) void wb_kernel(
    const float* __restrict__ W, ushort* __restrict__ Wb,
    int* __restrict__ bcur)
{
    int idx = blockIdx.x * 256 + threadIdx.x;      // 0..32767
    if (idx < NBUCK) bcur[idx] = idx * CAP;
    int j    = idx & 7;
    int lane = (idx >> 3) & 63;
    int nt   = (idx >> 9) & 7;
    int ks   = idx >> 12;
    int k = ks * 32 + (lane >> 4) * 8 + j;
    int n = nt * 16 + (lane & 15);
    Wb[idx] = f2bf(W[((size_t)(n >> 6) * IN_DIM + k) * OUT_DIM + (n & 63)]);
}

// ---------------------------------------------------------------------------
// Merged GEMM + BIN kernel: blocks [0, NBLK) run the R7-verbatim MFMA GEMM;
// blocks [NBLK, NBLK+BGRID) run the R7-verbatim rank-trick bin. The two
// roles are data-independent (gemm: x,Wb -> psb; bin: edges -> sbuf), so
// dispatch order across blocks is irrelevant. Co-residency overlaps gemm's
// MFMA/staging pipes with bin's BW/LDS-atomic pipes; also saves one launch.
// LDS is a union (gemm's 33.8 KB tile vs bin's 6.3 KB hist).
// ---------------------------------------------------------------------------
__global__ __launch_bounds__(256) void gb_kernel(
    const float* __restrict__ x, const ushort* __restrict__ Wb,
    ushort* __restrict__ psb,
    const int* __restrict__ edge_src, const int* __restrict__ edge_dst,
    const float* __restrict__ edge_val,
    int* __restrict__ bcur, u64* __restrict__ sbuf)
{
    __shared__ __align__(16) char smem[GM * 264 * 2];   // 33,792 B union

    if (blockIdx.x < NBLK) {
        // ----- GEMM role (R7-verbatim) -----
        ushort (*xs)[264] = (ushort (*)[264])smem;
        const int row0 = blockIdx.x * GM;
        const int trow = threadIdx.x >> 6;
        const int tcol = threadIdx.x & 63;

#pragma unroll
        for (int j = 0; j < 16; ++j) {
            int r = j * 4 + trow;
            int gr = row0 + r;
            if (gr > N_NODES - 1) gr = N_NODES - 1;
            float4 v = ((const float4*)x)[(size_t)gr * 64 + tcol];
            ushort4 h;
            h.x = f2bf(v.x); h.y = f2bf(v.y); h.z = f2bf(v.z); h.w = f2bf(v.w);
            *(ushort4*)&xs[r][tcol * 4] = h;
        }
        __syncthreads();

        const int wave = threadIdx.x >> 6;
        const int lane = threadIdx.x & 63;
        const int q = lane >> 4;
        const int m = lane & 15;
        const int nt0 = wave * 2;

        floatx4 acc[4][2];
#pragma unroll
        for (int mt = 0; mt < 4; ++mt)
#pragma unroll
            for (int nt = 0; nt < 2; ++nt)
                acc[mt][nt] = (floatx4){0.f, 0.f, 0.f, 0.f};

        const short8* Wbv = (const short8*)Wb;
#pragma unroll
        for (int ks = 0; ks < 8; ++ks) {
            short8 b0 = Wbv[((ks * 8) + nt0) * 64 + lane];
            short8 b1 = Wbv[((ks * 8) + nt0 + 1) * 64 + lane];
#pragma unroll
            for (int mt = 0; mt < 4; ++mt) {
                short8 a = *(const short8*)&xs[mt * 16 + m][ks * 32 + q * 8];
                acc[mt][0] = __builtin_amdgcn_mfma_f32_16x16x32_bf16(a, b0, acc[mt][0], 0, 0, 0);
                acc[mt][1] = __builtin_amdgcn_mfma_f32_16x16x32_bf16(a, b1, acc[mt][1], 0, 0, 0);
            }
        }

#pragma unroll
        for (int mt = 0; mt < 4; ++mt) {
#pragma unroll
            for (int nt = 0; nt < 2; ++nt) {
                int col = wave * 32 + nt * 16 + m;
                int sup = col >> 6, ch = col & 63;
#pragma unroll
                for (int r = 0; r < 4; ++r) {
                    int row = row0 + mt * 16 + q * 4 + r;
                    if (row < N_NODES)
                        psb[((size_t)sup * N_NODES + row) * OUT_DIM + ch] =
                            f2bf(acc[mt][nt][r]);
                }
            }
        }
    } else {
        // ----- BIN role (R7-verbatim rank trick) -----
        int* hist  = (int*)smem;            // NBUCK ints
        int* gbase = hist + NBUCK;          // NBUCK ints (total 6,256 B)
        const int bb = blockIdx.x - NBLK;
        const int base = bb * CHUNK + threadIdx.x;

        u64 pk[16];
        int bk[16];
        int rk[16];
        for (int i = threadIdx.x; i < NBUCK; i += 256) hist[i] = 0;
        __syncthreads();

#pragma unroll
        for (int j = 0; j < 16; ++j) {
            int gid = base + j * 256;
            bk[j] = -1;
            if (gid < N_TOT_EDGES) {
                int dst = edge_dst[gid];
                int src = edge_src[gid];
                float val = edge_val[gid];
                int srcsup = (gid >= N_EDGES ? N_NODES : 0) + src;
                bk[j] = dst >> SHIFT;
                pk[j] = ((u64)__float_as_uint(val) << 32)
                      | (u64)(((unsigned)srcsup << SHIFT) | (unsigned)(dst & (BUCKN - 1)));
                rk[j] = atomicAdd(&hist[bk[j]], 1);
            }
        }
        __syncthreads();
        for (int i = threadIdx.x; i < NBUCK; i += 256) {
            int h = hist[i];
            gbase[i] = h ? atomicAdd(&bcur[i], h) : 0;
        }
        __syncthreads();
#pragma unroll
        for (int j = 0; j < 16; ++j) {
            if (bk[j] >= 0) {
                size_t pos = (size_t)gbase[bk[j]] + rk[j];
                if (pos < (size_t)(bk[j] + 1) * CAP)   // safety clamp only
                    sbuf[pos] = pk[j];
            }
        }
    }
}

// ---------------------------------------------------------------------------
// Fused sort+gather. Sort phase R7-VERBATIM (single-pass rank-trick
// counting-sort into 36 KB LDS). Gather phase: unroll widened 16 -> 32 edges
// per iteration (8 srec reads + 8 psb ushort4 loads in flight = 2x memory-
// level parallelism). Same branchless-guard math, shfl_xor cross-group
// reduce, float4 store.
// ---------------------------------------------------------------------------
__global__ __launch_bounds__(512) void fused_kernel(
    const ushort* __restrict__ psb, const u64* __restrict__ sbuf,
    const int* __restrict__ bcur, float* __restrict__ out)
{
    __shared__ u64 srec[CAP];                        // 36,864 B
    __shared__ int h[BUCKN], sc[BUCKN], eb[BUCKN];   // 1.5 KB -> 38.4 KB total
    const int b = blockIdx.x;
    const int tid = threadIdx.x;

    int cnt = bcur[b] - b * CAP;
    if (cnt > CAP) cnt = CAP;
    const u64* sb = sbuf + (size_t)b * CAP;

    if (tid < BUCKN) h[tid] = 0;
    __syncthreads();

    // single global pass: records -> registers, rank from hist atomic
    u64 pk[9];
    int rk[9];
#pragma unroll
    for (int jj = 0; jj < 9; ++jj) {
        int i = tid + jj * 512;
        rk[jj] = -1;
        if (i < cnt) {
            pk[jj] = sb[i];
            rk[jj] = atomicAdd(&h[(int)(pk[jj] & (BUCKN - 1))], 1);
        }
    }
    __syncthreads();

    // inclusive Hillis-Steele scan over 128 counts
    if (tid < BUCKN) sc[tid] = h[tid];
    __syncthreads();
    for (int off = 1; off < BUCKN; off <<= 1) {
        int add = (tid < BUCKN && tid >= off) ? sc[tid - off] : 0;
        __syncthreads();
        if (tid < BUCKN) sc[tid] += add;
        __syncthreads();
    }
    if (tid < BUCKN) eb[tid] = sc[tid] - h[tid];    // exclusive base
    __syncthreads();

    // scatter from registers: slot = exclusive base + rank (bijective)
#pragma unroll
    for (int jj = 0; jj < 9; ++jj) {
        if (rk[jj] >= 0) {
            int node = (int)(pk[jj] & (BUCKN - 1));
            srec[eb[node] + rk[jj]] = pk[jj];
        }
    }
    __syncthreads();

    // gather phase: wave w owns local nodes w*16 .. w*16+15
    const int wave = tid >> 6;
    const int lane = tid & 63;
    const int grp  = lane >> 4;     // which edge of a 4-edge chunk
    const int cl   = lane & 15;     // which channel quad
    const int nbase = b << SHIFT;

    for (int t = 0; t < 16; ++t) {
        const int d = wave * 16 + t;
        const int e = sc[d];                       // uniform LDS reads
        const int s = e - h[d];
        float4 acc = {0.f, 0.f, 0.f, 0.f};

        for (int jb = s; jb < e; jb += 32) {       // 32 edges per iteration
            int i0 = jb + grp,      i1 = jb + 4 + grp;
            int i2 = jb + 8 + grp,  i3 = jb + 12 + grp;
            int i4 = jb + 16 + grp, i5 = jb + 20 + grp;
            int i6 = jb + 24 + grp, i7 = jb + 28 + grp;
            u64 r0 = 0, r1 = 0, r2 = 0, r3 = 0, r4 = 0, r5 = 0, r6 = 0, r7 = 0;
            if (i0 < e) r0 = srec[i0];
            if (i1 < e) r1 = srec[i1];
            if (i2 < e) r2 = srec[i2];
            if (i3 < e) r3 = srec[i3];
            if (i4 < e) r4 = srec[i4];
            if (i5 < e) r5 = srec[i5];
            if (i6 < e) r6 = srec[i6];
            if (i7 < e) r7 = srec[i7];
            // rec==0 => val bits 0 => fma adds 0; row 0 load is harmless
            float v0 = __uint_as_float((unsigned)(r0 >> 32));
            float v1 = __uint_as_float((unsigned)(r1 >> 32));
            float v2 = __uint_as_float((unsigned)(r2 >> 32));
            float v3 = __uint_as_float((unsigned)(r3 >> 32));
            float v4 = __uint_as_float((unsigned)(r4 >> 32));
            float v5 = __uint_as_float((unsigned)(r5 >> 32));
            float v6 = __uint_as_float((unsigned)(r6 >> 32));
            float v7 = __uint_as_float((unsigned)(r7 >> 32));
            unsigned w0 = (unsigned)r0 >> SHIFT;
            unsigned w1 = (unsigned)r1 >> SHIFT;
            unsigned w2 = (unsigned)r2 >> SHIFT;
            unsigned w3 = (unsigned)r3 >> SHIFT;
            unsigned w4 = (unsigned)r4 >> SHIFT;
            unsigned w5 = (unsigned)r5 >> SHIFT;
            unsigned w6 = (unsigned)r6 >> SHIFT;
            unsigned w7 = (unsigned)r7 >> SHIFT;
            ushort4 p0 = *(const ushort4*)&psb[(size_t)w0 * OUT_DIM + cl * 4];
            ushort4 p1 = *(const ushort4*)&psb[(size_t)w1 * OUT_DIM + cl * 4];
            ushort4 p2 = *(const ushort4*)&psb[(size_t)w2 * OUT_DIM + cl * 4];
            ushort4 p3 = *(const ushort4*)&psb[(size_t)w3 * OUT_DIM + cl * 4];
            ushort4 p4 = *(const ushort4*)&psb[(size_t)w4 * OUT_DIM + cl * 4];
            ushort4 p5 = *(const ushort4*)&psb[(size_t)w5 * OUT_DIM + cl * 4];
            ushort4 p6 = *(const ushort4*)&psb[(size_t)w6 * OUT_DIM + cl * 4];
            ushort4 p7 = *(const ushort4*)&psb[(size_t)w7 * OUT_DIM + cl * 4];
            acc.x = fmaf(bf2f(p0.x), v0, acc.x);
            acc.y = fmaf(bf2f(p0.y), v0, acc.y);
            acc.z = fmaf(bf2f(p0.z), v0, acc.z);
            acc.w = fmaf(bf2f(p0.w), v0, acc.w);
            acc.x = fmaf(bf2f(p1.x), v1, acc.x);
            acc.y = fmaf(bf2f(p1.y), v1, acc.y);
            acc.z = fmaf(bf2f(p1.z), v1, acc.z);
            acc.w = fmaf(bf2f(p1.w), v1, acc.w);
            acc.x = fmaf(bf2f(p2.x), v2, acc.x);
            acc.y = fmaf(bf2f(p2.y), v2, acc.y);
            acc.z = fmaf(bf2f(p2.z), v2, acc.z);
            acc.w = fmaf(bf2f(p2.w), v2, acc.w);
            acc.x = fmaf(bf2f(p3.x), v3, acc.x);
            acc.y = fmaf(bf2f(p3.y), v3, acc.y);
            acc.z = fmaf(bf2f(p3.z), v3, acc.z);
            acc.w = fmaf(bf2f(p3.w), v3, acc.w);
            acc.x = fmaf(bf2f(p4.x), v4, acc.x);
            acc.y = fmaf(bf2f(p4.y), v4, acc.y);
            acc.z = fmaf(bf2f(p4.z), v4, acc.z);
            acc.w = fmaf(bf2f(p4.w), v4, acc.w);
            acc.x = fmaf(bf2f(p5.x), v5, acc.x);
            acc.y = fmaf(bf2f(p5.y), v5, acc.y);
            acc.z = fmaf(bf2f(p5.z), v5, acc.z);
            acc.w = fmaf(bf2f(p5.w), v5, acc.w);
            acc.x = fmaf(bf2f(p6.x), v6, acc.x);
            acc.y = fmaf(bf2f(p6.y), v6, acc.y);
            acc.z = fmaf(bf2f(p6.z), v6, acc.z);
            acc.w = fmaf(bf2f(p6.w), v6, acc.w);
            acc.x = fmaf(bf2f(p7.x), v7, acc.x);
            acc.y = fmaf(bf2f(p7.y), v7, acc.y);
            acc.z = fmaf(bf2f(p7.z), v7, acc.z);
            acc.w = fmaf(bf2f(p7.w), v7, acc.w);
        }

        // reduce the 4 edge-groups (channels cl*4.. live in lanes cl, cl+16, cl+32, cl+48)
        acc.x += __shfl_xor(acc.x, 16); acc.x += __shfl_xor(acc.x, 32);
        acc.y += __shfl_xor(acc.y, 16); acc.y += __shfl_xor(acc.y, 32);
        acc.z += __shfl_xor(acc.z, 16); acc.z += __shfl_xor(acc.z, 32);
        acc.w += __shfl_xor(acc.w, 16); acc.w += __shfl_xor(acc.w, 32);

        const int node = nbase + d;
        if (lane < 16 && node < N_NODES) {
            acc.x = fmaxf(acc.x, 0.f); acc.y = fmaxf(acc.y, 0.f);
            acc.z = fmaxf(acc.z, 0.f); acc.w = fmaxf(acc.w, 0.f);
            ((float4*)out)[(size_t)node * 16 + cl] = acc;
        }
    }
}

extern "C" void kernel_launch(void* const* d_in, const int* in_sizes, int n_in,
                              void* d_out, int out_size, void* d_ws, size_t ws_size,
                              hipStream_t stream)
{
    const float* x        = (const float*)d_in[0];
    const float* W        = (const float*)d_in[1];
    const float* edge_val = (const float*)d_in[2];
    const int*   edge_src = (const int*)d_in[3];
    const int*   edge_dst = (const int*)d_in[4];
    float* out = (float*)d_out;

    // workspace layout (total 54,496,768 B, well under proven 77.67 MB):
    //   psb  [2*100000*64 bf16]   @ 0           (25,600,000)
    //   sbuf [782*4608 u64]       @ 25,600,000  (28,827,648)  fixed-cap staging
    //   bcur [782 int]            @ 54,427,648  (3,128)
    //   Wb   [32768 ushort]       @ 54,431,232  (65,536)  16B-aligned
    ushort* psb = (ushort*)d_ws;
    char* p = (char*)d_ws;
    u64*  sbuf = (u64*)(p + 25600000);
    int*  bcur = (int*)(p + 54427648);
    ushort* Wb = (ushort*)(p + 54431232);

    wb_kernel<<<128, 256, 0, stream>>>(W, Wb, bcur);
    gb_kernel<<<NBLK + BGRID, 256, 0, stream>>>(x, Wb, psb,
                                                edge_src, edge_dst, edge_val,
                                                bcur, sbuf);
    fused_kernel<<<NBUCK, 512, 0, stream>>>(psb, sbuf, bcur, out);
}